// Round 6
// baseline (347.580 us; speedup 1.0000x reference)
//
#include <hip/hip_runtime.h>

#define NE 4000
#define NI 1000
#define NT 5000            // total neurons
#define PI_F 3.14159265358979323846f
#define ST 65              // LDS tile row stride (floats): 64 + 1 pad

#define NB_SIM ((NT + 63) / 64)     // 79 sim blocks (1 wave each, 1 neuron/lane)
#define NB_TOT 1024                 // rest are zero-filler blocks

// d_out layout (floats): [0,T) Out | [T, T+NT*T) V | next NT*T g | next NT*T spk

// One Euler step in u = tan(theta/2):  u += kk*I - hh + hh*u^2 ;  V = 3.5u - 58.5
#define USTEP(W, VO) {                          \
    float a_ = fmaf(kk, (W), mh);               \
    float s_ = u + a_;                          \
    u = fmaf(hh * u, u, s_);                    \
    umax = fmaxf(umax, u);                      \
    VO = fmaf(3.5f, u, -58.5f);                 \
}

// Cooperative tile load: 64 rows x 16 float4 cols, clamped (duplicates benign).
// Each instr: 4 rows x 256B contiguous segments.
#define LOADT(c0v, dst) {                                           \
    _Pragma("unroll")                                               \
    for (int it_ = 0; it_ < 16; ++it_) {                            \
        int row_ = i0 + it_ * 4 + (lane >> 4);                      \
        row_ = row_ < NT ? row_ : NT - 1;                           \
        int col_ = (c0v) + 4 * (lane & 15);                         \
        col_ = col_ <= T - 4 ? col_ : T - 4;                        \
        dst[it_] = *(const float4*)(Input + (long)row_ * T + col_); \
    } }

// regs -> LDS tile (direct static-array indexing => real ds_write_b128)
#define WTILE(BUF, src) {                                           \
    _Pragma("unroll")                                               \
    for (int it_ = 0; it_ < 16; ++it_) {                            \
        int rr_ = it_ * 4 + (lane >> 4);                            \
        *(float4*)(&BUF[rr_ * ST + 4 * (lane & 15)]) = src[it_];    \
    } }

// Batch-read own row into regs FIRST (one DS latency), then 64 USTEPs -> VT.
#define COMPUTE(BUF, first_, nq_) {                                 \
    float4 wv_[16];                                                 \
    _Pragma("unroll")                                               \
    for (int j_ = 0; j_ < 16; ++j_) {                               \
        if (j_ < (nq_))                                             \
            wv_[j_] = *(const float4*)(&BUF[lane * ST + 4 * j_]);   \
    }                                                               \
    _Pragma("unroll")                                               \
    for (int j_ = 0; j_ < 16; ++j_) {                               \
        if (j_ < (nq_)) {                                           \
            float4 v_;                                              \
            if ((first_) && j_ == 0) { v_.x = -58.5f; }             \
            else { USTEP(wv_[j_].x, v_.x); }                        \
            USTEP(wv_[j_].y, v_.y);                                 \
            USTEP(wv_[j_].z, v_.z);                                 \
            USTEP(wv_[j_].w, v_.w);                                 \
            *(float4*)(&VT[lane * ST + 4 * j_]) = v_;               \
        }                                                           \
    } }

// VT -> global V, coalesced (4 rows x 256B per instr), rows clamped.
#define STORET(c0v, nq_) {                                          \
    _Pragma("unroll")                                               \
    for (int it_ = 0; it_ < 16; ++it_) {                            \
        int qq_ = lane & 15;                                        \
        if (qq_ < (nq_)) {                                          \
            int rr_ = it_ * 4 + (lane >> 4);                        \
            float4 v_ = *(const float4*)(&VT[rr_ * ST + 4 * qq_]);  \
            int row_ = i0 + rr_; row_ = row_ < NT ? row_ : NT - 1;  \
            *(float4*)(V + (long)row_ * T + (c0v) + 4 * qq_) = v_;  \
        }                                                           \
    } }

__global__ __launch_bounds__(64, 1) void sim_nospike(
    const float* __restrict__ Input, const float* __restrict__ dtp,
    float* __restrict__ out, int T, int* __restrict__ flags)
{
    const int lane = threadIdx.x;
    const int b = blockIdx.x;

    if (b >= NB_SIM) {                       // ---- zeroing path (full-chip BW) ----
        const float4 z4 = make_float4(0.f, 0.f, 0.f, 0.f);
        long zidx = (long)(b - NB_SIM) * 64 + lane;
        long zstr = (long)(NB_TOT - NB_SIM) * 64;
        float4* gz = (float4*)(out + T + (long)NT * T);   // g+spk contiguous
        const long n4 = (long)NT * T / 2;
        for (long k = zidx; k < n4; k += zstr) gz[k] = z4;
        if (b == NB_SIM) {
            float4* oz = (float4*)out;
            for (int x = lane; x < T / 4; x += 64) oz[x] = z4;
        }
        return;
    }

    __shared__ float A0[64 * ST];
    __shared__ float A1[64 * ST];
    __shared__ float VT[64 * ST];

    const int i0 = b * 64;
    int i = i0 + lane; if (i >= NT) i = NT - 1;
    const float dt = dtp[0];
    const float gl = (i < NE) ? 0.08f : 0.1f;
    const float kk = (2.0f / 7.0f) * dt;     // C0*dt
    const float hh = 0.5f * gl * dt;
    const float mh = -hh;
    float* V = out + T;
    float u = 0.f, umax = -1e30f;

    if (T >= 64 && (T & 3) == 0) {
        const int NCH  = T >> 6;             // full 64-step chunks
        const int remq = (T & 63) >> 2;      // remaining float4 groups (T=1000 -> 10)
        const int NCHT = NCH + (remq ? 1 : 0);
        float4 tmp[16];

        LOADT(0, tmp);
        WTILE(A0, tmp);                      // one exposed vmcnt wait (prologue only)
        if (NCHT > 1) LOADT(64, tmp);        // prefetch chunk 1

        for (int c = 0; c < NCHT; ++c) {
            int nq = (c < NCH) ? 16 : remq;
            if (c + 1 < NCHT) {              // drain chunk c+1 (issued 1 chunk ago)
                if ((c + 1) & 1) { WTILE(A1, tmp); }
                else             { WTILE(A0, tmp); }
            }
            if (c + 2 < NCHT) LOADT((c + 2) * 64, tmp);   // deep prefetch
            if (c & 1) { COMPUTE(A1, false, nq); }
            else       { COMPUTE(A0, c == 0, nq); }
            STORET(c * 64, nq);
        }
    } else {
        // generic scalar path (not taken for T=1000)
        const float* ip = Input + (long)i * T;
        float* vrow = V + (long)i * T;
        for (int t = 0; t < T; ++t) {
            float w = ip[t], v;
            if (t == 0) { v = -58.5f; }
            else        { USTEP(w, v); }
            vrow[t] = v;
        }
    }

    // conservative spike flag: theta >= pi requires crossing u = tan(theta/2) >= 1
    unsigned long long ball = __ballot(umax >= 1.0f);
    if (lane == 0) flags[b] = (ball != 0ULL) ? 1 : 0;
}

// Exact sequential fallback (only executes if a spike was flagged).
__global__ __launch_bounds__(1024) void fallback(
    const float* __restrict__ Input, const float* __restrict__ conn,
    const float* __restrict__ Wout, const float* __restrict__ dtp,
    const int* __restrict__ tauEp, const int* __restrict__ tauIp,
    float* __restrict__ out, int T, const int* __restrict__ flags, int nb)
{
    __shared__ int any;
    const int tid = threadIdx.x;
    if (tid == 0) any = 0;
    __syncthreads();
    if (tid < nb && flags[tid] != 0) any = 1;
    __syncthreads();
    if (any == 0) return;                   // uniform: optimistic path valid

    const float dt = *dtp;
    const float tauE = (float)(*tauEp), tauI = (float)(*tauIp);
    const float C0 = (float)(2.0 / 7.0);
    const float C1 = (float)(117.0 / 7.0);
    const float C2 = (float)(-23.0 / 7.0);
    const int BLK = 1024;
    const int K = 5;                        // 5*1024 >= 5000

    __shared__ int cntE, cntI;
    __shared__ int listE[NE];
    __shared__ int listI[NI];
    __shared__ float red[1024];

    float gA[K], gB[K], gC[K], ph[K];
    for (int k = 0; k < K; ++k) { gA[k] = gB[k] = gC[k] = 0.f; ph[k] = 0.f; }
    if (tid == 0) { cntE = 0; cntI = 0; }

    float* Vout = out + T;
    float* Gout = out + T + (long)NT * T;
    float* Sout = out + T + 2L * (long)NT * T;
    for (int k = 0; k < K; ++k) {
        int i = tid + k * BLK;
        if (i < NT) Vout[(long)i * T] = -58.5f;
    }
    __syncthreads();

    for (int t = 1; t < T; ++t) {
        int nEs = cntE, nIs = cntI;         // spikes from step t-1
        float outpart = 0.f;
        for (int k = 0; k < K; ++k) {
            int i = tid + k * BLK;
            if (i >= NT) break;
            const float* crow = conn + (long)i * NT;
            float mA = 0.f, mB = 0.f;
            for (int j = 0; j < nEs; ++j) mA += crow[listE[j]];
            for (int j = 0; j < nIs; ++j) mB += crow[listI[j]];
            bool isE = i < NE;
            float tau = isE ? tauE : tauI;
            float gpA = isE ? 0.004069f : 0.003276f;
            float gpB = isE ? 0.02672f  : 0.02138f;
            gA[k] = gA[k] + (-gA[k] / tau + gpA * mA) * dt;
            gB[k] = gB[k] + (-gB[k] / tau + gpB * mB) * dt;
            gC[k] = gC[k] + (-gC[k] / tau + gpA * mA + gpB * mB) * dt;
            Gout[(long)i * T + t] = gC[k];
            outpart += gC[k] * Wout[i];
        }
        __syncthreads();                    // all done reading lists
        if (tid == 0) { cntE = 0; cntI = 0; }
        red[tid] = outpart;
        __syncthreads();
        for (int sd = BLK / 2; sd > 0; sd >>= 1) {
            if (tid < sd) red[tid] += red[tid + sd];
            __syncthreads();
        }
        if (tid == 0) out[t] = red[0] / (float)NT;

        for (int k = 0; k < K; ++k) {
            int i = tid + k * BLK;
            if (i >= NT) break;
            bool isE = i < NE;
            float gl = isE ? 0.08f : 0.1f;
            float inp = Input[(long)i * T + t];
            float s, c;
            sincosf(ph[k], &s, &c);
            float ph2 = ph[k] + (-gl * c + C0 * (1.f + c) * inp
                                 + gA[k] * (C1 * (1.f + c) - s)
                                 + gB[k] * (C2 * (1.f + c) - s)) * dt;
            float spkv = 0.f;
            if (ph2 >= PI_F) {
                spkv = 1.f;
                ph2 -= 2.f * PI_F;
                int pos = isE ? atomicAdd(&cntE, 1) : atomicAdd(&cntI, 1);
                if (isE) listE[pos] = i; else listI[pos] = i;
            }
            ph[k] = ph2;
            Sout[(long)i * T + t] = spkv;
            Vout[(long)i * T + t] = fmaf(3.5f, tanf(ph2 * 0.5f), -58.5f);
        }
        __syncthreads();                    // lists complete for next step
    }
}

extern "C" void kernel_launch(void* const* d_in, const int* in_sizes, int n_in,
                              void* d_out, int out_size, void* d_ws, size_t ws_size,
                              hipStream_t stream)
{
    const float* dt    = (const float*)d_in[0];
    const float* Input = (const float*)d_in[1];
    const float* conn  = (const float*)d_in[2];
    const float* Wout  = (const float*)d_in[3];
    const int*   tauE  = (const int*)d_in[6];
    const int*   tauI  = (const int*)d_in[7];
    int T = in_sizes[1] / NT;
    float* out = (float*)d_out;
    int* flags = (int*)d_ws;

    sim_nospike<<<NB_TOT, 64, 0, stream>>>(Input, dt, out, T, flags);
    fallback<<<1, 1024, 0, stream>>>(Input, conn, Wout, dt, tauE, tauI, out, T, flags, NB_SIM);
}

// Round 7
// 209.472 us; speedup vs baseline: 1.6593x; 1.6593x over previous
//
#include <hip/hip_runtime.h>

#define NE 4000
#define NI 1000
#define NT 5000            // total neurons
#define PI_F 3.14159265358979323846f

#define NB_SIM ((NT + 63) / 64)     // 79 sim blocks (1 wave each, 1 neuron/lane)
#define NB_TOT 1024                 // rest are zero-filler blocks

// d_out layout (floats): [0,T) Out | [T, T+NT*T) V | next NT*T g | next NT*T spk

// One Euler step in u = tan(theta/2):  u += kk*I - hh + hh*u^2 ;  V = 3.5u - 58.5
#define U1(W, VV) { float a_ = fmaf(kk, (W), mh); float s_ = u + a_;    \
                    u = fmaf(hh * u, u, s_); umax = fmaxf(umax, u);     \
                    VV = fmaf(3.5f, u, -58.5f); }

// load one 16-step chunk (4 x dwordx4) into a named buffer set
#define LDm(P0, P1, P2, P3, cc) { const float* sp_ = ip + (cc) * 16;    \
    P0 = *(const float4*)(sp_);      P1 = *(const float4*)(sp_ + 4);    \
    P2 = *(const float4*)(sp_ + 8);  P3 = *(const float4*)(sp_ + 12); }

// process one 16-step chunk from a named buffer set; store V (4 x dwordx4)
#define PROCm(P0, P1, P2, P3, cc) {                                     \
    float4 v0_, v1_, v2_, v3_; int t0_ = (cc) * 16;                     \
    if (t0_ == 0) { v0_.x = -58.5f; }   /* t=0: V=theta2V(0) */         \
    else          { U1(P0.x, v0_.x) }                                   \
    U1(P0.y, v0_.y) U1(P0.z, v0_.z) U1(P0.w, v0_.w)                     \
    U1(P1.x, v1_.x) U1(P1.y, v1_.y) U1(P1.z, v1_.z) U1(P1.w, v1_.w)     \
    U1(P2.x, v2_.x) U1(P2.y, v2_.y) U1(P2.z, v2_.z) U1(P2.w, v2_.w)     \
    U1(P3.x, v3_.x) U1(P3.y, v3_.y) U1(P3.z, v3_.z) U1(P3.w, v3_.w)     \
    float* dp_ = vrow + t0_;                                            \
    *(float4*)(dp_)     = v0_;  *(float4*)(dp_ + 4)  = v1_;             \
    *(float4*)(dp_ + 8) = v2_;  *(float4*)(dp_ + 12) = v3_; }

__global__ __launch_bounds__(64) void sim_nospike(
    const float* __restrict__ Input, const float* __restrict__ dtp,
    float* __restrict__ out, int T, int* __restrict__ flags)
{
    const int lane = threadIdx.x;
    const int b = blockIdx.x;

    if (b >= NB_SIM) {                       // ---- zeroing path (full-chip BW) ----
        const float4 z4 = make_float4(0.f, 0.f, 0.f, 0.f);
        long zidx = (long)(b - NB_SIM) * 64 + lane;
        long zstr = (long)(NB_TOT - NB_SIM) * 64;
        float4* gz = (float4*)(out + T + (long)NT * T);   // g+spk contiguous
        const long n4 = (long)NT * T / 2;
        for (long k = zidx; k < n4; k += zstr) gz[k] = z4;
        if (b == NB_SIM) {
            float4* oz = (float4*)out;
            for (int x = lane; x < T / 4; x += 64) oz[x] = z4;
        }
        return;
    }

    int i = b * 64 + lane; if (i >= NT) i = NT - 1;   // clamp: dup work, benign
    const float dt = dtp[0];
    const float gl = (i < NE) ? 0.08f : 0.1f;
    const float kk = (2.0f / 7.0f) * dt;     // C0*dt
    const float hh = 0.5f * gl * dt;
    const float mh = -hh;
    const float* ip = Input + (long)i * T;
    float* vrow = out + T + (long)i * T;
    float u = 0.f, umax = -1e30f;

    const int nch = ((T & 3) == 0) ? (T >> 4) : 0;    // 16-step chunks (62 @ T=1000)

    // 4 named buffer sets; loads issued 3 sections (~750 cyc) before use.
    float4 A0, A1, A2, A3, B0, B1, B2, B3, C0f, C1f, C2f, C3f, D0, D1, D2, D3;

    if (nch > 0) LDm(A0, A1, A2, A3, 0);
    if (nch > 1) LDm(B0, B1, B2, B3, 1);
    if (nch > 2) LDm(C0f, C1f, C2f, C3f, 2);

    int c = 0;
    for (; c + 4 <= nch; c += 4) {
        if (c + 3 < nch) LDm(D0, D1, D2, D3, c + 3);
        PROCm(A0, A1, A2, A3, c);
        if (c + 4 < nch) LDm(A0, A1, A2, A3, c + 4);
        PROCm(B0, B1, B2, B3, c + 1);
        if (c + 5 < nch) LDm(B0, B1, B2, B3, c + 5);
        PROCm(C0f, C1f, C2f, C3f, c + 2);
        if (c + 6 < nch) LDm(C0f, C1f, C2f, C3f, c + 6);
        PROCm(D0, D1, D2, D3, c + 3);
    }
    if (c < nch)     PROCm(A0, A1, A2, A3, c);
    if (c + 1 < nch) PROCm(B0, B1, B2, B3, c + 1);
    if (c + 2 < nch) PROCm(C0f, C1f, C2f, C3f, c + 2);

    // scalar tail (T=1000 -> 8 steps; also the generic path when T%4 != 0)
    for (int t = nch * 16; t < T; ++t) {
        float w = ip[t], v;
        if (t == 0) { v = -58.5f; }
        else        { U1(w, v) }
        vrow[t] = v;
    }

    // conservative spike flag: theta >= pi requires crossing u = tan(theta/2) >= 1
    unsigned long long ball = __ballot(umax >= 1.0f);
    if (lane == 0) flags[b] = (ball != 0ULL) ? 1 : 0;
}

// Exact sequential fallback (only executes if a spike was flagged).
__global__ __launch_bounds__(1024) void fallback(
    const float* __restrict__ Input, const float* __restrict__ conn,
    const float* __restrict__ Wout, const float* __restrict__ dtp,
    const int* __restrict__ tauEp, const int* __restrict__ tauIp,
    float* __restrict__ out, int T, const int* __restrict__ flags, int nb)
{
    __shared__ int any;
    const int tid = threadIdx.x;
    if (tid == 0) any = 0;
    __syncthreads();
    if (tid < nb && flags[tid] != 0) any = 1;
    __syncthreads();
    if (any == 0) return;                   // uniform: optimistic path valid

    const float dt = *dtp;
    const float tauE = (float)(*tauEp), tauI = (float)(*tauIp);
    const float C0 = (float)(2.0 / 7.0);
    const float C1 = (float)(117.0 / 7.0);
    const float C2 = (float)(-23.0 / 7.0);
    const int BLK = 1024;
    const int K = 5;                        // 5*1024 >= 5000

    __shared__ int cntE, cntI;
    __shared__ int listE[NE];
    __shared__ int listI[NI];
    __shared__ float red[1024];

    float gA[K], gB[K], gC[K], ph[K];
    for (int k = 0; k < K; ++k) { gA[k] = gB[k] = gC[k] = 0.f; ph[k] = 0.f; }
    if (tid == 0) { cntE = 0; cntI = 0; }

    float* Vout = out + T;
    float* Gout = out + T + (long)NT * T;
    float* Sout = out + T + 2L * (long)NT * T;
    for (int k = 0; k < K; ++k) {
        int i = tid + k * BLK;
        if (i < NT) Vout[(long)i * T] = -58.5f;
    }
    __syncthreads();

    for (int t = 1; t < T; ++t) {
        int nEs = cntE, nIs = cntI;         // spikes from step t-1
        float outpart = 0.f;
        for (int k = 0; k < K; ++k) {
            int i = tid + k * BLK;
            if (i >= NT) break;
            const float* crow = conn + (long)i * NT;
            float mA = 0.f, mB = 0.f;
            for (int j = 0; j < nEs; ++j) mA += crow[listE[j]];
            for (int j = 0; j < nIs; ++j) mB += crow[listI[j]];
            bool isE = i < NE;
            float tau = isE ? tauE : tauI;
            float gpA = isE ? 0.004069f : 0.003276f;
            float gpB = isE ? 0.02672f  : 0.02138f;
            gA[k] = gA[k] + (-gA[k] / tau + gpA * mA) * dt;
            gB[k] = gB[k] + (-gB[k] / tau + gpB * mB) * dt;
            gC[k] = gC[k] + (-gC[k] / tau + gpA * mA + gpB * mB) * dt;
            Gout[(long)i * T + t] = gC[k];
            outpart += gC[k] * Wout[i];
        }
        __syncthreads();                    // all done reading lists
        if (tid == 0) { cntE = 0; cntI = 0; }
        red[tid] = outpart;
        __syncthreads();
        for (int sd = BLK / 2; sd > 0; sd >>= 1) {
            if (tid < sd) red[tid] += red[tid + sd];
            __syncthreads();
        }
        if (tid == 0) out[t] = red[0] / (float)NT;

        for (int k = 0; k < K; ++k) {
            int i = tid + k * BLK;
            if (i >= NT) break;
            bool isE = i < NE;
            float gl = isE ? 0.08f : 0.1f;
            float inp = Input[(long)i * T + t];
            float s, c;
            sincosf(ph[k], &s, &c);
            float ph2 = ph[k] + (-gl * c + C0 * (1.f + c) * inp
                                 + gA[k] * (C1 * (1.f + c) - s)
                                 + gB[k] * (C2 * (1.f + c) - s)) * dt;
            float spkv = 0.f;
            if (ph2 >= PI_F) {
                spkv = 1.f;
                ph2 -= 2.f * PI_F;
                int pos = isE ? atomicAdd(&cntE, 1) : atomicAdd(&cntI, 1);
                if (isE) listE[pos] = i; else listI[pos] = i;
            }
            ph[k] = ph2;
            Sout[(long)i * T + t] = spkv;
            Vout[(long)i * T + t] = fmaf(3.5f, tanf(ph2 * 0.5f), -58.5f);
        }
        __syncthreads();                    // lists complete for next step
    }
}

extern "C" void kernel_launch(void* const* d_in, const int* in_sizes, int n_in,
                              void* d_out, int out_size, void* d_ws, size_t ws_size,
                              hipStream_t stream)
{
    const float* dt    = (const float*)d_in[0];
    const float* Input = (const float*)d_in[1];
    const float* conn  = (const float*)d_in[2];
    const float* Wout  = (const float*)d_in[3];
    const int*   tauE  = (const int*)d_in[6];
    const int*   tauI  = (const int*)d_in[7];
    int T = in_sizes[1] / NT;
    float* out = (float*)d_out;
    int* flags = (int*)d_ws;

    sim_nospike<<<NB_TOT, 64, 0, stream>>>(Input, dt, out, T, flags);
    fallback<<<1, 1024, 0, stream>>>(Input, conn, Wout, dt, tauE, tauI, out, T, flags, NB_SIM);
}